// Round 2
// baseline (2048.095 us; speedup 1.0000x reference)
//
#include <hip/hip_runtime.h>
#include <hip/hip_bf16.h>

#define PTS 8192
#define NSPLIT 2

// ---------------- top-16 (smallest) maintenance, fully static indexing ----------------
__device__ __forceinline__ void top_init(float (&bd)[16], int (&bi)[16]) {
#pragma unroll
  for (int t = 0; t < 16; ++t) { bd[t] = 3e38f; bi[t] = 0; }
}

// sorted ascending; bd[15] is current worst
__device__ __forceinline__ void top_insert(float (&bd)[16], int (&bi)[16], float d, int j) {
  if (d < bd[15]) {
#pragma unroll
    for (int t = 15; t >= 0; --t) {
      bool c  = d < bd[t];
      bool cp = (t > 0) ? (d < bd[t - 1]) : false;
      float nd = cp ? bd[t - 1] : d;
      int   ni = cp ? bi[t - 1] : j;
      if (c) { bd[t] = nd; bi[t] = ni; }
    }
  }
}

// ---------------- squared norms ----------------
__global__ void sqnorm_kernel(const float* __restrict__ h, float* __restrict__ sq, int C) {
  int i = blockIdx.x * 256 + threadIdx.x;
  if (i >= PTS) return;
  const float* r = h + (size_t)i * C;
  float s = 0.f;
  for (int k = 0; k < C; ++k) s += r[k] * r[k];
  sq[i] = s;
}

// ---------------- fused pairwise-distance + per-row top-16 ----------------
// grid = (PTS/64, NSPLIT). Block: 256 thr. 64 rows x 64-col tiles, 4x4 micro-tile.
// Per row: 4 threads keep private top-16 over their candidate slice; partials to global.
template <int C>
__global__ __launch_bounds__(256) void knn_kernel(const float* __restrict__ H,
                                                  const float* __restrict__ sq,
                                                  float* __restrict__ pd,
                                                  int* __restrict__ pi) {
  __shared__ float As[16][68];   // [k][row], rows 16B-aligned (68*4=272)
  __shared__ float Bs[16][68];   // [k][col]
  __shared__ float D2[64][65];   // distance tile, stride 65 => conflict-free column reads
  const int tid  = threadIdx.x;
  const int row0 = blockIdx.x * 64;
  const int cb   = blockIdx.y * (PTS / NSPLIT);
  const int tx = tid & 15, ty = tid >> 4;
  const int r_ = tid & 63, p_ = tid >> 6;

  float sqr[4];
#pragma unroll
  for (int u = 0; u < 4; ++u) sqr[u] = sq[row0 + ty * 4 + u];

  float bd[16]; int bi[16];
  top_init(bd, bi);

  for (int ct = 0; ct < PTS / NSPLIT; ct += 64) {
    float acc[4][4] = {};
    for (int k0 = 0; k0 < C; k0 += 16) {
      __syncthreads();  // prior tile's LDS reads (incl. D2 scan) complete
#pragma unroll
      for (int l = 0; l < 4; ++l) {
        int rr = (tid >> 4) + l * 16;
        int kk = tid & 15;
        float va = 0.f, vb = 0.f;
        if (k0 + kk < C) {
          va = H[(size_t)(row0 + rr) * C + k0 + kk];
          vb = H[(size_t)(cb + ct + rr) * C + k0 + kk];
        }
        As[kk][rr] = va;
        Bs[kk][rr] = vb;
      }
      __syncthreads();
#pragma unroll
      for (int k = 0; k < 16; ++k) {
        float4 a4 = *(const float4*)&As[k][ty * 4];
        float4 b4 = *(const float4*)&Bs[k][tx * 4];
        float a[4] = {a4.x, a4.y, a4.z, a4.w};
        float b[4] = {b4.x, b4.y, b4.z, b4.w};
#pragma unroll
        for (int u = 0; u < 4; ++u)
#pragma unroll
          for (int v = 0; v < 4; ++v)
            acc[u][v] += a[u] * b[v];
      }
    }
    float sqc[4];
#pragma unroll
    for (int v = 0; v < 4; ++v) sqc[v] = sq[cb + ct + tx * 4 + v];
#pragma unroll
    for (int u = 0; u < 4; ++u) {
      int gr = row0 + ty * 4 + u;
#pragma unroll
      for (int v = 0; v < 4; ++v) {
        int gc = cb + ct + tx * 4 + v;
        float d2 = sqr[u] + sqc[v] - 2.f * acc[u][v];
        if (gr == gc) d2 = 3e38f;   // exclude self like the reference
        D2[ty * 4 + u][tx * 4 + v] = d2;
      }
    }
    __syncthreads();
#pragma unroll
    for (int q = 0; q < 16; ++q) {
      float d = D2[r_][p_ * 16 + q];
      top_insert(bd, bi, d, cb + ct + p_ * 16 + q);
    }
  }
  size_t base = ((size_t)(row0 + r_) * (NSPLIT * 4) + blockIdx.y * 4 + p_) * 16;
#pragma unroll
  for (int t = 0; t < 16; ++t) { pd[base + t] = bd[t]; pi[base + t] = bi[t]; }
}

__global__ void knn_merge_kernel(const float* __restrict__ pd, const int* __restrict__ pi,
                                 int* __restrict__ idx) {
  int i = blockIdx.x * 256 + threadIdx.x;
  if (i >= PTS) return;
  float bd[16]; int bi[16];
  top_init(bd, bi);
  const float* d  = pd + (size_t)i * (NSPLIT * 4 * 16);
  const int*   ii = pi + (size_t)i * (NSPLIT * 4 * 16);
  for (int t = 0; t < NSPLIT * 4 * 16; ++t) top_insert(bd, bi, d[t], ii[t]);
#pragma unroll
  for (int t = 0; t < 16; ++t) idx[(size_t)i * 16 + t] = bi[t];
}

// ---------------- tiled f32 GEMM computing F = A@Wt + bias (z=0) and G = A@Wb (z=1) ----------------
__global__ __launch_bounds__(256) void gemm_fg_kernel(const float* __restrict__ A,
                                                      const float* __restrict__ Wt,
                                                      const float* __restrict__ Wb,
                                                      const float* __restrict__ bias,
                                                      float* __restrict__ F, float* __restrict__ G,
                                                      int K, int N) {
  __shared__ float As[16][68];
  __shared__ float Bs[16][68];
  const int tid  = threadIdx.x;
  const int row0 = blockIdx.x * 64, col0 = blockIdx.y * 64;
  const float* B = (blockIdx.z == 0) ? Wt : Wb;
  float* O       = (blockIdx.z == 0) ? F  : G;
  const int tx = tid & 15, ty = tid >> 4;
  float acc[4][4] = {};
  for (int k0 = 0; k0 < K; k0 += 16) {
    __syncthreads();
#pragma unroll
    for (int l = 0; l < 4; ++l) {
      int rr = (tid >> 4) + l * 16, kk = tid & 15;
      As[kk][rr] = (k0 + kk < K) ? A[(size_t)(row0 + rr) * K + k0 + kk] : 0.f;
      int cc = tid & 63, k2 = (tid >> 6) + l * 4;
      Bs[k2][cc] = (k0 + k2 < K) ? B[(size_t)(k0 + k2) * N + col0 + cc] : 0.f;
    }
    __syncthreads();
#pragma unroll
    for (int k = 0; k < 16; ++k) {
      float4 a4 = *(const float4*)&As[k][ty * 4];
      float4 b4 = *(const float4*)&Bs[k][tx * 4];
      float a[4] = {a4.x, a4.y, a4.z, a4.w};
      float b[4] = {b4.x, b4.y, b4.z, b4.w};
#pragma unroll
      for (int u = 0; u < 4; ++u)
#pragma unroll
        for (int v = 0; v < 4; ++v)
          acc[u][v] += a[u] * b[v];
    }
  }
  float bv[4] = {0.f, 0.f, 0.f, 0.f};
  if (blockIdx.z == 0) {
#pragma unroll
    for (int v = 0; v < 4; ++v) bv[v] = bias[col0 + tx * 4 + v];
  }
#pragma unroll
  for (int u = 0; u < 4; ++u)
#pragma unroll
    for (int v = 0; v < 4; ++v)
      O[(size_t)(row0 + ty * 4 + u) * N + col0 + tx * 4 + v] = acc[u][v] + bv[v];
}

// ---------------- out_i = relu(F_i - G_i + max_{j in idx_i} G_j) ----------------
__global__ void gather_max_kernel(const float* __restrict__ F, const float* __restrict__ G,
                                  const int* __restrict__ idx, float* __restrict__ Ho, int Cn) {
  int t = blockIdx.x * 256 + threadIdx.x;
  int per = Cn >> 2;
  int i = t / per;
  if (i >= PTS) return;
  int c = (t - i * per) * 4;
  const int* ji = idx + (size_t)i * 16;
  float4 m = make_float4(-3e38f, -3e38f, -3e38f, -3e38f);
#pragma unroll
  for (int s = 0; s < 16; ++s) {
    float4 v = *(const float4*)(G + (size_t)ji[s] * Cn + c);
    m.x = fmaxf(m.x, v.x); m.y = fmaxf(m.y, v.y);
    m.z = fmaxf(m.z, v.z); m.w = fmaxf(m.w, v.w);
  }
  float4 gi = *(const float4*)(G + (size_t)i * Cn + c);
  float4 f  = *(const float4*)(F + (size_t)i * Cn + c);
  float4 o;
  o.x = fmaxf(f.x - gi.x + m.x, 0.f);
  o.y = fmaxf(f.y - gi.y + m.y, 0.f);
  o.z = fmaxf(f.z - gi.z + m.z, 0.f);
  o.w = fmaxf(f.w - gi.w + m.w, 0.f);
  *(float4*)(Ho + (size_t)i * Cn + c) = o;
}

// ---------------- final MLP: out = relu(h3@fW1+fb1)@fW2 + fb2 ----------------
__global__ __launch_bounds__(256) void mlp_kernel(const float* __restrict__ h3,
                                                  const float* __restrict__ fW1,
                                                  const float* __restrict__ fb1,
                                                  const float* __restrict__ fW2,
                                                  const float* __restrict__ fb2,
                                                  float* __restrict__ out) {
  __shared__ float hs[16][260];   // 16 points x 256 dims (stride 1040B, 16B-aligned)
  __shared__ float ws[64][128];   // fW1 k-chunk
  __shared__ float red[4][8];
  const int tid = threadIdx.x;
  const int p0  = blockIdx.x * 16;
#pragma unroll
  for (int l = 0; l < 16; ++l) {
    int ii = l * 256 + tid;
    hs[ii >> 8][ii & 255] = h3[(size_t)(p0 + (ii >> 8)) * 256 + (ii & 255)];
  }
  const int c = tid & 127, half = tid >> 7;
  float acc[8];
#pragma unroll
  for (int pp = 0; pp < 8; ++pp) acc[pp] = fb1[c];
  for (int k0 = 0; k0 < 256; k0 += 64) {
    __syncthreads();
#pragma unroll
    for (int l = 0; l < 32; ++l) {
      int ii = l * 256 + tid;
      ws[ii >> 7][ii & 127] = fW1[(size_t)(k0 + (ii >> 7)) * 128 + (ii & 127)];
    }
    __syncthreads();
    for (int k = 0; k < 64; k += 4) {
      float w0 = ws[k][c], w1 = ws[k + 1][c], w2 = ws[k + 2][c], w3 = ws[k + 3][c];
#pragma unroll
      for (int pp = 0; pp < 8; ++pp) {
        float4 h4 = *(const float4*)&hs[half * 8 + pp][k0 + k];
        acc[pp] += h4.x * w0 + h4.y * w1 + h4.z * w2 + h4.w * w3;
      }
    }
  }
  float w2v = fW2[c];
  float s[8];
#pragma unroll
  for (int pp = 0; pp < 8; ++pp) s[pp] = fmaxf(acc[pp], 0.f) * w2v;
#pragma unroll
  for (int off = 32; off > 0; off >>= 1) {
#pragma unroll
    for (int pp = 0; pp < 8; ++pp) s[pp] += __shfl_down(s[pp], off);
  }
  if ((tid & 63) == 0) {
#pragma unroll
    for (int pp = 0; pp < 8; ++pp) red[tid >> 6][pp] = s[pp];
  }
  __syncthreads();
  if (tid < 16) {
    int hf = tid >> 3, pp = tid & 7;
    float v = red[hf * 2][pp] + red[hf * 2 + 1][pp] + fb2[0];
    out[p0 + hf * 8 + pp] = v;
  }
}

// ---------------- host ----------------
extern "C" void kernel_launch(void* const* d_in, const int* in_sizes, int n_in,
                              void* d_out, int out_size, void* d_ws, size_t ws_size,
                              hipStream_t stream) {
  (void)in_sizes; (void)n_in; (void)out_size; (void)ws_size;
  const float* x   = (const float*)d_in[0];
  const float* W1  = (const float*)d_in[1];
  const float* b1  = (const float*)d_in[2];
  const float* W2  = (const float*)d_in[3];
  const float* b2  = (const float*)d_in[4];
  const float* W3  = (const float*)d_in[5];
  const float* b3  = (const float*)d_in[6];
  const float* fW1 = (const float*)d_in[7];
  const float* fb1 = (const float*)d_in[8];
  const float* fW2 = (const float*)d_in[9];
  const float* fb2 = (const float*)d_in[10];

  float* w = (float*)d_ws;
  size_t o = 0;
  float* sq  = w + o; o += PTS;
  float* h1  = w + o; o += (size_t)PTS * 64;
  float* h2  = w + o; o += (size_t)PTS * 128;
  float* h3  = w + o; o += (size_t)PTS * 256;
  float* F   = w + o; o += (size_t)PTS * 256;
  float* G   = w + o; o += (size_t)PTS * 256;
  float* pd  = w + o; o += (size_t)PTS * 128;
  int*   pi  = (int*)(w + o); o += (size_t)PTS * 128;
  int*   idx = (int*)(w + o); o += (size_t)PTS * 16;

  // ---- layer 1 (C=3 -> 64) ----
  sqnorm_kernel<<<PTS / 256, 256, 0, stream>>>(x, sq, 3);
  knn_kernel<3><<<dim3(PTS / 64, NSPLIT), 256, 0, stream>>>(x, sq, pd, pi);
  knn_merge_kernel<<<PTS / 256, 256, 0, stream>>>(pd, pi, idx);
  gemm_fg_kernel<<<dim3(PTS / 64, 1, 2), 256, 0, stream>>>(x, W1, W1 + 3 * 64, b1, F, G, 3, 64);
  gather_max_kernel<<<(PTS * 16 + 255) / 256, 256, 0, stream>>>(F, G, idx, h1, 64);

  // ---- layer 2 (C=64 -> 128) ----
  sqnorm_kernel<<<PTS / 256, 256, 0, stream>>>(h1, sq, 64);
  knn_kernel<64><<<dim3(PTS / 64, NSPLIT), 256, 0, stream>>>(h1, sq, pd, pi);
  knn_merge_kernel<<<PTS / 256, 256, 0, stream>>>(pd, pi, idx);
  gemm_fg_kernel<<<dim3(PTS / 64, 2, 2), 256, 0, stream>>>(h1, W2, W2 + 64 * 128, b2, F, G, 64, 128);
  gather_max_kernel<<<(PTS * 32 + 255) / 256, 256, 0, stream>>>(F, G, idx, h2, 128);

  // ---- layer 3 (C=128 -> 256) ----
  sqnorm_kernel<<<PTS / 256, 256, 0, stream>>>(h2, sq, 128);
  knn_kernel<128><<<dim3(PTS / 64, NSPLIT), 256, 0, stream>>>(h2, sq, pd, pi);
  knn_merge_kernel<<<PTS / 256, 256, 0, stream>>>(pd, pi, idx);
  gemm_fg_kernel<<<dim3(PTS / 64, 4, 2), 256, 0, stream>>>(h2, W3, W3 + 128 * 256, b3, F, G, 128, 256);
  gather_max_kernel<<<(PTS * 64 + 255) / 256, 256, 0, stream>>>(F, G, idx, h3, 256);

  // ---- final MLP ----
  mlp_kernel<<<PTS / 16, 256, 0, stream>>>(h3, fW1, fb1, fW2, fb2, (float*)d_out);
}

// Round 3
// 1846.324 us; speedup vs baseline: 1.1093x; 1.1093x over previous
//
#include <hip/hip_runtime.h>
#include <hip/hip_bf16.h>

#define PTS 8192
#define NSPLIT 8

// ---------------- top-16 (smallest) maintenance, fully static indexing ----------------
__device__ __forceinline__ void top_init(float (&bd)[16], int (&bi)[16]) {
#pragma unroll
  for (int t = 0; t < 16; ++t) { bd[t] = 3e38f; bi[t] = 0; }
}

// sorted ascending; bd[15] is current worst
__device__ __forceinline__ void top_insert(float (&bd)[16], int (&bi)[16], float d, int j) {
  if (d < bd[15]) {
#pragma unroll
    for (int t = 15; t >= 0; --t) {
      bool c  = d < bd[t];
      bool cp = (t > 0) ? (d < bd[t - 1]) : false;
      float nd = cp ? bd[t - 1] : d;
      int   ni = cp ? bi[t - 1] : j;
      if (c) { bd[t] = nd; bi[t] = ni; }
    }
  }
}

// ---------------- squared norms ----------------
__global__ void sqnorm_kernel(const float* __restrict__ h, float* __restrict__ sq, int C) {
  int i = blockIdx.x * 256 + threadIdx.x;
  if (i >= PTS) return;
  const float* r = h + (size_t)i * C;
  float s = 0.f;
  for (int k = 0; k < C; ++k) s += r[k] * r[k];
  sq[i] = s;
}

// ---------------- fused pairwise-distance + per-row top-16 ----------------
// grid = (PTS/64, NSPLIT), 256 thr. 64 rows x 64-col tiles, 4x4 micro-tile, 32-k chunks.
// Wave w scans col-quarter w of each tile; per-wave top-16 merged in-block by wave 0.
template <int C>
__global__ __launch_bounds__(256, 4) void knn_kernel(const float* __restrict__ H,
                                                     const float* __restrict__ sq,
                                                     float* __restrict__ pd,
                                                     int* __restrict__ pi) {
  __shared__ float smem[2 * 32 * 68 + 64 * 68];
  float* As = smem;                 // [32][68]  k-major, row minor
  float* Bs = smem + 32 * 68;       // [32][68]
  float* D2 = smem + 2 * 32 * 68;   // [64][68]
  const int tid  = threadIdx.x;
  const int row0 = blockIdx.x * 64;
  const int cb   = blockIdx.y * (PTS / NSPLIT);
  const int tx = tid & 15, ty = tid >> 4;
  const int r_ = tid & 63, p_ = tid >> 6;
  constexpr int KL = (C < 32) ? C : 32;

  float sqr[4];
#pragma unroll
  for (int u = 0; u < 4; ++u) sqr[u] = sq[row0 + ty * 4 + u];

  float bd[16]; int bi[16];
  top_init(bd, bi);

  for (int ct = 0; ct < PTS / NSPLIT; ct += 64) {
    float acc[4][4] = {};
    for (int k0 = 0; k0 < C; k0 += 32) {
      __syncthreads();  // prior chunk's LDS reads (incl. D2 scan) complete
#pragma unroll
      for (int l = 0; l < 8; ++l) {
        int rr = (tid >> 5) + l * 8;
        int kk = tid & 31;
        float va = 0.f, vb = 0.f;
        if (k0 + kk < C) {
          va = H[(size_t)(row0 + rr) * C + k0 + kk];
          vb = H[(size_t)(cb + ct + rr) * C + k0 + kk];
        }
        As[kk * 68 + rr] = va;
        Bs[kk * 68 + rr] = vb;
      }
      __syncthreads();
#pragma unroll
      for (int k = 0; k < KL; ++k) {
        float4 a4 = *(const float4*)(As + k * 68 + ty * 4);
        float4 b4 = *(const float4*)(Bs + k * 68 + tx * 4);
        float a[4] = {a4.x, a4.y, a4.z, a4.w};
        float b[4] = {b4.x, b4.y, b4.z, b4.w};
#pragma unroll
        for (int u = 0; u < 4; ++u)
#pragma unroll
          for (int v = 0; v < 4; ++v)
            acc[u][v] += a[u] * b[v];
      }
    }
    float sqc[4];
#pragma unroll
    for (int v = 0; v < 4; ++v) sqc[v] = sq[cb + ct + tx * 4 + v];
#pragma unroll
    for (int u = 0; u < 4; ++u) {
      int row = ty * 4 + u;
      int gr  = row0 + row;
      float dv[4];
#pragma unroll
      for (int v = 0; v < 4; ++v) {
        float d2 = sqr[u] + sqc[v] - 2.f * acc[u][v];
        if (gr == cb + ct + tx * 4 + v) d2 = 3e38f;  // exclude self
        dv[v] = d2;
      }
      *(float4*)(D2 + row * 68 + tx * 4) = make_float4(dv[0], dv[1], dv[2], dv[3]);
    }
    __syncthreads();
#pragma unroll
    for (int q = 0; q < 16; ++q) {
      int cc = p_ * 16 + ((q + r_) & 15);   // per-lane rotation: conflict-free at stride 68
      float d = D2[r_ * 68 + cc];
      top_insert(bd, bi, d, cb + ct + cc);
    }
  }

  // ---- in-block merge of the 4 per-wave lists (wave 0 merges) ----
  __syncthreads();
  if (p_ > 0) {
    int* iTmp = (int*)smem;
#pragma unroll
    for (int t = 0; t < 16; ++t) {
      D2[r_ * 68 + p_ * 16 + t]        = bd[t];
      iTmp[r_ * 48 + (p_ - 1) * 16 + t] = bi[t];
    }
  }
  __syncthreads();
  if (p_ == 0) {
    const int* iTmp = (const int*)smem;
    for (int L = 1; L < 4; ++L) {
      for (int t = 0; t < 16; ++t) {
        float d = D2[r_ * 68 + L * 16 + t];
        if (d >= bd[15]) break;             // lists are sorted ascending
        top_insert(bd, bi, d, iTmp[r_ * 48 + (L - 1) * 16 + t]);
      }
    }
    size_t base = ((size_t)(row0 + r_) * NSPLIT + blockIdx.y) * 16;
#pragma unroll
    for (int t = 0; t < 16; ++t) { pd[base + t] = bd[t]; pi[base + t] = bi[t]; }
  }
}

__global__ void knn_merge_kernel(const float* __restrict__ pd, const int* __restrict__ pi,
                                 int* __restrict__ idx) {
  int i = blockIdx.x * 256 + threadIdx.x;
  if (i >= PTS) return;
  float bd[16]; int bi[16];
  top_init(bd, bi);
  const float* d  = pd + (size_t)i * (NSPLIT * 16);
  const int*   ii = pi + (size_t)i * (NSPLIT * 16);
  for (int L = 0; L < NSPLIT; ++L) {
    for (int t = 0; t < 16; ++t) {
      float dv = d[L * 16 + t];
      if (dv >= bd[15]) break;              // sorted sublists
      top_insert(bd, bi, dv, ii[L * 16 + t]);
    }
  }
#pragma unroll
  for (int t = 0; t < 16; ++t) idx[(size_t)i * 16 + t] = bi[t];
}

// ---------------- tiled f32 GEMM computing F = A@Wt + bias (z=0) and G = A@Wb (z=1) ----------------
__global__ __launch_bounds__(256) void gemm_fg_kernel(const float* __restrict__ A,
                                                      const float* __restrict__ Wt,
                                                      const float* __restrict__ Wb,
                                                      const float* __restrict__ bias,
                                                      float* __restrict__ F, float* __restrict__ G,
                                                      int K, int N) {
  __shared__ float As[16][68];
  __shared__ float Bs[16][68];
  const int tid  = threadIdx.x;
  const int row0 = blockIdx.x * 64, col0 = blockIdx.y * 64;
  const float* B = (blockIdx.z == 0) ? Wt : Wb;
  float* O       = (blockIdx.z == 0) ? F  : G;
  const int tx = tid & 15, ty = tid >> 4;
  float acc[4][4] = {};
  for (int k0 = 0; k0 < K; k0 += 16) {
    __syncthreads();
#pragma unroll
    for (int l = 0; l < 4; ++l) {
      int rr = (tid >> 4) + l * 16, kk = tid & 15;
      As[kk][rr] = (k0 + kk < K) ? A[(size_t)(row0 + rr) * K + k0 + kk] : 0.f;
      int cc = tid & 63, k2 = (tid >> 6) + l * 4;
      Bs[k2][cc] = (k0 + k2 < K) ? B[(size_t)(k0 + k2) * N + col0 + cc] : 0.f;
    }
    __syncthreads();
#pragma unroll
    for (int k = 0; k < 16; ++k) {
      float4 a4 = *(const float4*)&As[k][ty * 4];
      float4 b4 = *(const float4*)&Bs[k][tx * 4];
      float a[4] = {a4.x, a4.y, a4.z, a4.w};
      float b[4] = {b4.x, b4.y, b4.z, b4.w};
#pragma unroll
      for (int u = 0; u < 4; ++u)
#pragma unroll
        for (int v = 0; v < 4; ++v)
          acc[u][v] += a[u] * b[v];
    }
  }
  float bv[4] = {0.f, 0.f, 0.f, 0.f};
  if (blockIdx.z == 0) {
#pragma unroll
    for (int v = 0; v < 4; ++v) bv[v] = bias[col0 + tx * 4 + v];
  }
#pragma unroll
  for (int u = 0; u < 4; ++u)
#pragma unroll
    for (int v = 0; v < 4; ++v)
      O[(size_t)(row0 + ty * 4 + u) * N + col0 + tx * 4 + v] = acc[u][v] + bv[v];
}

// ---------------- out_i = relu(F_i - G_i + max_{j in idx_i} G_j) ----------------
__global__ void gather_max_kernel(const float* __restrict__ F, const float* __restrict__ G,
                                  const int* __restrict__ idx, float* __restrict__ Ho, int Cn) {
  int t = blockIdx.x * 256 + threadIdx.x;
  int per = Cn >> 2;
  int i = t / per;
  if (i >= PTS) return;
  int c = (t - i * per) * 4;
  const int* ji = idx + (size_t)i * 16;
  float4 m = make_float4(-3e38f, -3e38f, -3e38f, -3e38f);
#pragma unroll
  for (int s = 0; s < 16; ++s) {
    float4 v = *(const float4*)(G + (size_t)ji[s] * Cn + c);
    m.x = fmaxf(m.x, v.x); m.y = fmaxf(m.y, v.y);
    m.z = fmaxf(m.z, v.z); m.w = fmaxf(m.w, v.w);
  }
  float4 gi = *(const float4*)(G + (size_t)i * Cn + c);
  float4 f  = *(const float4*)(F + (size_t)i * Cn + c);
  float4 o;
  o.x = fmaxf(f.x - gi.x + m.x, 0.f);
  o.y = fmaxf(f.y - gi.y + m.y, 0.f);
  o.z = fmaxf(f.z - gi.z + m.z, 0.f);
  o.w = fmaxf(f.w - gi.w + m.w, 0.f);
  *(float4*)(Ho + (size_t)i * Cn + c) = o;
}

// ---------------- final MLP: out = relu(h3@fW1+fb1)@fW2 + fb2 ----------------
__global__ __launch_bounds__(256) void mlp_kernel(const float* __restrict__ h3,
                                                  const float* __restrict__ fW1,
                                                  const float* __restrict__ fb1,
                                                  const float* __restrict__ fW2,
                                                  const float* __restrict__ fb2,
                                                  float* __restrict__ out) {
  __shared__ float hs[16][260];
  __shared__ float ws[64][128];
  __shared__ float red[4][8];
  const int tid = threadIdx.x;
  const int p0  = blockIdx.x * 16;
#pragma unroll
  for (int l = 0; l < 16; ++l) {
    int ii = l * 256 + tid;
    hs[ii >> 8][ii & 255] = h3[(size_t)(p0 + (ii >> 8)) * 256 + (ii & 255)];
  }
  const int c = tid & 127, half = tid >> 7;
  float acc[8];
#pragma unroll
  for (int pp = 0; pp < 8; ++pp) acc[pp] = fb1[c];
  for (int k0 = 0; k0 < 256; k0 += 64) {
    __syncthreads();
#pragma unroll
    for (int l = 0; l < 32; ++l) {
      int ii = l * 256 + tid;
      ws[ii >> 7][ii & 127] = fW1[(size_t)(k0 + (ii >> 7)) * 128 + (ii & 127)];
    }
    __syncthreads();
    for (int k = 0; k < 64; k += 4) {
      float w0 = ws[k][c], w1 = ws[k + 1][c], w2 = ws[k + 2][c], w3 = ws[k + 3][c];
#pragma unroll
      for (int pp = 0; pp < 8; ++pp) {
        float4 h4 = *(const float4*)&hs[half * 8 + pp][k0 + k];
        acc[pp] += h4.x * w0 + h4.y * w1 + h4.z * w2 + h4.w * w3;
      }
    }
  }
  float w2v = fW2[c];
  float s[8];
#pragma unroll
  for (int pp = 0; pp < 8; ++pp) s[pp] = fmaxf(acc[pp], 0.f) * w2v;
#pragma unroll
  for (int off = 32; off > 0; off >>= 1) {
#pragma unroll
    for (int pp = 0; pp < 8; ++pp) s[pp] += __shfl_down(s[pp], off);
  }
  if ((tid & 63) == 0) {
#pragma unroll
    for (int pp = 0; pp < 8; ++pp) red[tid >> 6][pp] = s[pp];
  }
  __syncthreads();
  if (tid < 16) {
    int hf = tid >> 3, pp = tid & 7;
    float v = red[hf * 2][pp] + red[hf * 2 + 1][pp] + fb2[0];
    out[p0 + hf * 8 + pp] = v;
  }
}

// ---------------- host ----------------
extern "C" void kernel_launch(void* const* d_in, const int* in_sizes, int n_in,
                              void* d_out, int out_size, void* d_ws, size_t ws_size,
                              hipStream_t stream) {
  (void)in_sizes; (void)n_in; (void)out_size; (void)ws_size;
  const float* x   = (const float*)d_in[0];
  const float* W1  = (const float*)d_in[1];
  const float* b1  = (const float*)d_in[2];
  const float* W2  = (const float*)d_in[3];
  const float* b2  = (const float*)d_in[4];
  const float* W3  = (const float*)d_in[5];
  const float* b3  = (const float*)d_in[6];
  const float* fW1 = (const float*)d_in[7];
  const float* fb1 = (const float*)d_in[8];
  const float* fW2 = (const float*)d_in[9];
  const float* fb2 = (const float*)d_in[10];

  float* w = (float*)d_ws;
  size_t o = 0;
  float* sq  = w + o; o += PTS;
  float* h1  = w + o; o += (size_t)PTS * 64;
  float* h2  = w + o; o += (size_t)PTS * 128;
  float* h3  = w + o; o += (size_t)PTS * 256;
  float* F   = w + o; o += (size_t)PTS * 256;
  float* G   = w + o; o += (size_t)PTS * 256;
  float* pd  = w + o; o += (size_t)PTS * 128;
  int*   pi  = (int*)(w + o); o += (size_t)PTS * 128;
  int*   idx = (int*)(w + o); o += (size_t)PTS * 16;

  // ---- layer 1 (C=3 -> 64) ----
  sqnorm_kernel<<<PTS / 256, 256, 0, stream>>>(x, sq, 3);
  knn_kernel<3><<<dim3(PTS / 64, NSPLIT), 256, 0, stream>>>(x, sq, pd, pi);
  knn_merge_kernel<<<PTS / 256, 256, 0, stream>>>(pd, pi, idx);
  gemm_fg_kernel<<<dim3(PTS / 64, 1, 2), 256, 0, stream>>>(x, W1, W1 + 3 * 64, b1, F, G, 3, 64);
  gather_max_kernel<<<(PTS * 16 + 255) / 256, 256, 0, stream>>>(F, G, idx, h1, 64);

  // ---- layer 2 (C=64 -> 128) ----
  sqnorm_kernel<<<PTS / 256, 256, 0, stream>>>(h1, sq, 64);
  knn_kernel<64><<<dim3(PTS / 64, NSPLIT), 256, 0, stream>>>(h1, sq, pd, pi);
  knn_merge_kernel<<<PTS / 256, 256, 0, stream>>>(pd, pi, idx);
  gemm_fg_kernel<<<dim3(PTS / 64, 2, 2), 256, 0, stream>>>(h1, W2, W2 + 64 * 128, b2, F, G, 64, 128);
  gather_max_kernel<<<(PTS * 32 + 255) / 256, 256, 0, stream>>>(F, G, idx, h2, 128);

  // ---- layer 3 (C=128 -> 256) ----
  sqnorm_kernel<<<PTS / 256, 256, 0, stream>>>(h2, sq, 128);
  knn_kernel<128><<<dim3(PTS / 64, NSPLIT), 256, 0, stream>>>(h2, sq, pd, pi);
  knn_merge_kernel<<<PTS / 256, 256, 0, stream>>>(pd, pi, idx);
  gemm_fg_kernel<<<dim3(PTS / 64, 4, 2), 256, 0, stream>>>(h2, W3, W3 + 128 * 256, b3, F, G, 128, 256);
  gather_max_kernel<<<(PTS * 64 + 255) / 256, 256, 0, stream>>>(F, G, idx, h3, 256);

  // ---- final MLP ----
  mlp_kernel<<<PTS / 16, 256, 0, stream>>>(h3, fW1, fb1, fW2, fb2, (float*)d_out);
}